// Round 1
// baseline (7895.422 us; speedup 1.0000x reference)
//
#include <hip/hip_runtime.h>
#include <math.h>
#include <stdint.h>

// Problem constants
constexpr int LL = 4096;   // seq len
constexpr int EE = 300;    // embedding dim
constexpr int HH = 256;    // per-direction hidden (H2)
constexpr int NGATE = 1024;// 4*HH
constexpr int TT = 16;     // tagset
constexpr float NEGV = -10000.0f;

typedef _Float16 v2h __attribute__((ext_vector_type(2)));

// Workspace layout (byte offsets) — SLOT/MIR region retained (unused now)
constexpr size_t OFF_X    = 16384;
constexpr size_t OFF_ZX   = OFF_X    + (size_t)LL*EE*4;     // 2*L*1024 f32
constexpr size_t OFF_HALL = OFF_ZX   + (size_t)2*LL*NGATE*4;// 2*L*256 f32
constexpr size_t OFF_FE   = OFF_HALL + (size_t)2*LL*HH*4;   // L*16 f32

// Pack two f32 to f16x2 (RTZ)
__device__ __forceinline__ v2h pack_h2(float x, float y) {
  return __builtin_bit_cast(v2h, __builtin_amdgcn_cvt_pkrtz(x, y));
}
__device__ __forceinline__ unsigned pack_u(float x, float y) {
  return __builtin_bit_cast(unsigned, __builtin_amdgcn_cvt_pkrtz(x, y));
}
__device__ __forceinline__ v2h u2h(unsigned u) {
  return __builtin_bit_cast(v2h, u);
}

__device__ __forceinline__ float fsigmoid(float x) {
  return __builtin_amdgcn_rcpf(1.f + __expf(-x));
}
__device__ __forceinline__ float ftanh(float x) {
  return 1.f - 2.f * __builtin_amdgcn_rcpf(1.f + __expf(2.f * x));
}

// DPP helpers (quad_perm patterns verified in viterbi)
template <int CTRL>
__device__ __forceinline__ int dpp_i(int v) {
  return __builtin_amdgcn_mov_dpp(v, CTRL, 0xF, 0xF, true);
}
template <int CTRL>
__device__ __forceinline__ float dpp_f(float v) {
  return __int_as_float(__builtin_amdgcn_mov_dpp(__float_as_int(v), CTRL, 0xF, 0xF, true));
}
__device__ __forceinline__ float bperm_f(int lane, float v) {
  return __int_as_float(__builtin_amdgcn_ds_bpermute(lane << 2, __float_as_int(v)));
}

// ---------------------------------------------------------------------------
// Kernel 1: embedding gather
// ---------------------------------------------------------------------------
__global__ void gather_x(const int* __restrict__ sent, const float* __restrict__ emb,
                         float* __restrict__ X) {
  const int i = blockIdx.x * blockDim.x + threadIdx.x;
  const int total = LL * (EE / 4);
  if (i >= total) return;
  const int row = i / (EE / 4), c4 = i % (EE / 4);
  const int v = sent[row];
  reinterpret_cast<float4*>(X)[(size_t)row * (EE / 4) + c4] =
      reinterpret_cast<const float4*>(emb + (size_t)v * EE)[c4];
}

// ---------------------------------------------------------------------------
// Kernel 2: input GEMM  Zx[dir][t][n] = X[t]·W_ih[n] + b[n]
// ---------------------------------------------------------------------------
__global__ __launch_bounds__(256) void input_gemm(
    const float* __restrict__ X, const float* __restrict__ w_f,
    const float* __restrict__ b_f, const float* __restrict__ w_b,
    const float* __restrict__ b_b, float* __restrict__ ZX) {
  const int dir = blockIdx.z;
  const float* __restrict__ W  = dir ? w_b : w_f;
  const float* __restrict__ Bv = dir ? b_b : b_f;
  float* __restrict__ Z = ZX + (size_t)dir * LL * NGATE;
  __shared__ float As[32][68];
  __shared__ float Bs[32][68];
  const int m0 = blockIdx.y * 64, n0 = blockIdx.x * 64;
  const int t = threadIdx.x;
  const int tx = t & 15, ty = t >> 4;
  float acc[4][4] = {};
  for (int k0 = 0; k0 < EE; k0 += 32) {
#pragma unroll
    for (int r = 0; r < 2; ++r) {
      const int idx = t + r * 256;
      const int row = idx >> 3;
      const int kk4 = (idx & 7) << 2;
      const int k = k0 + kk4;
      float4 va = make_float4(0.f, 0.f, 0.f, 0.f), vb = va;
      if (k < EE) {
        va = *reinterpret_cast<const float4*>(X + (size_t)(m0 + row) * EE + k);
        vb = *reinterpret_cast<const float4*>(W + (size_t)(n0 + row) * EE + k);
      }
      As[kk4 + 0][row] = va.x; As[kk4 + 1][row] = va.y;
      As[kk4 + 2][row] = va.z; As[kk4 + 3][row] = va.w;
      Bs[kk4 + 0][row] = vb.x; Bs[kk4 + 1][row] = vb.y;
      Bs[kk4 + 2][row] = vb.z; Bs[kk4 + 3][row] = vb.w;
    }
    __syncthreads();
    const int kmax = (EE - k0 < 32) ? (EE - k0) : 32;
    for (int k = 0; k < kmax; ++k) {
      const float4 av = *reinterpret_cast<const float4*>(&As[k][ty << 2]);
      const float4 bv = *reinterpret_cast<const float4*>(&Bs[k][tx << 2]);
      acc[0][0] += av.x * bv.x; acc[0][1] += av.x * bv.y; acc[0][2] += av.x * bv.z; acc[0][3] += av.x * bv.w;
      acc[1][0] += av.y * bv.x; acc[1][1] += av.y * bv.y; acc[1][2] += av.y * bv.z; acc[1][3] += av.y * bv.w;
      acc[2][0] += av.z * bv.x; acc[2][1] += av.z * bv.y; acc[2][2] += av.z * bv.z; acc[2][3] += av.z * bv.w;
      acc[3][0] += av.w * bv.x; acc[3][1] += av.w * bv.y; acc[3][2] += av.w * bv.z; acc[3][3] += av.w * bv.w;
    }
    __syncthreads();
  }
#pragma unroll
  for (int i = 0; i < 4; ++i)
#pragma unroll
    for (int j = 0; j < 4; ++j) {
      const int m = m0 + (ty << 2) + i, n = n0 + (tx << 2) + j;
      Z[(size_t)m * NGATE + n] = acc[i][j] + Bv[n];
    }
}

// ---------------------------------------------------------------------------
// Kernel 3: persistent bidirectional LSTM recurrence — SINGLE WG per direction.
//
// Previous structure (4 WGs/dir + L2/LLC polling) measured 3650 cy/step with
// VALUBusy 0.77%: ~93% of each step was cross-WG h-exchange latency. This
// version keeps the ENTIRE direction on one CU: no polling, no agent-scope
// atomics, one s_barrier per step.
//
// Weight residency for W_hh (1024x256 f32 -> f16 pairs = 512 KB):
//   * thread (rq = t>>2 in [0,128), kq = t&3) owns rows rq+128j (j=0..7)
//     -> gate j>>1, unit rq+128*(j&1); k-slice {32kq..+31} U {128+32kq..+31}
//     packed as 32 (lo,hi) f16 pairs with hi = lo+128 (k-permutation is
//     legal: dot products are order-invariant).
//   * pairs 0..23  -> 192 VGPRs/thread (384 KB total, pinned via asm)
//   * pairs 24..31 -> 128 KiB LDS, laid out so a wave reads contiguous 16 B
//     chunks (conflict-free ds_read_b128)
// h is double-buffered in LDS as packed (h[d], h[d+128]) dwords; the pair
// producers are adjacent lanes in a quad -> pack via quad_perm 0xB1 DPP.
// k-partials reduce across the quad with the 0xB1/0x4E DPP butterfly.
// Per-step floor: 256 v_dot2_f32_f16/thread (~1024 cy/SIMD) overlapped with
// the 128 KB/step LDS weight stream -> ~1500-1800 cy/step vs 3650 before.
// ---------------------------------------------------------------------------
__global__ __launch_bounds__(512) __attribute__((amdgpu_waves_per_eu(2, 2)))
void recurrence(
    const float* __restrict__ whh_f, const float* __restrict__ whh_b,
    const float* __restrict__ h0, const float* __restrict__ c0,
    const float* __restrict__ ZX, float* __restrict__ HALL) {
  const int dir = blockIdx.x;
  const int t = threadIdx.x;
  const int rq = t >> 2;           // 0..127
  const int kq = t & 3;            // k-slice id
  const int u  = rq + ((kq & 1) << 7);  // unit for gate lanes (kq<2): rq or rq+128
  const float* __restrict__ Whh = dir ? whh_b : whh_f;
  const float* __restrict__ Z = ZX + (size_t)dir * LL * NGATE;
  float* __restrict__ Hall = HALL + (size_t)dir * LL * HH;

  __shared__ uint4 wl[8192];                        // 128 KiB LDS-resident weight pairs 24..31
  __shared__ __align__(16) unsigned h2[2][4][36];   // packed h, padded rows (bank spread)

  // ---- preamble: load + pack W_hh ----------------------------------------
  v2h w2[8][24];
  {
    const int klo = kq << 5;
#pragma unroll
    for (int j = 0; j < 8; ++j) {
      const int row = rq + (j << 7);
      const float* wr = Whh + (size_t)row * HH + klo;
#pragma unroll
      for (int m = 0; m < 6; ++m) {
        const float4 lo = *reinterpret_cast<const float4*>(wr + 4 * m);
        const float4 hi = *reinterpret_cast<const float4*>(wr + 128 + 4 * m);
        w2[j][4 * m + 0] = pack_h2(lo.x, hi.x);
        w2[j][4 * m + 1] = pack_h2(lo.y, hi.y);
        w2[j][4 * m + 2] = pack_h2(lo.z, hi.z);
        w2[j][4 * m + 3] = pack_h2(lo.w, hi.w);
      }
      const float4 lo0 = *reinterpret_cast<const float4*>(wr + 24);
      const float4 hi0 = *reinterpret_cast<const float4*>(wr + 128 + 24);
      const float4 lo1 = *reinterpret_cast<const float4*>(wr + 28);
      const float4 hi1 = *reinterpret_cast<const float4*>(wr + 128 + 28);
      uint4 p0, p1;
      p0.x = pack_u(lo0.x, hi0.x); p0.y = pack_u(lo0.y, hi0.y);
      p0.z = pack_u(lo0.z, hi0.z); p0.w = pack_u(lo0.w, hi0.w);
      p1.x = pack_u(lo1.x, hi1.x); p1.y = pack_u(lo1.y, hi1.y);
      p1.z = pack_u(lo1.z, hi1.z); p1.w = pack_u(lo1.w, hi1.w);
      wl[(((j << 1) | 0) << 9) + t] = p0;
      wl[(((j << 1) | 1) << 9) + t] = p1;
    }
  }
  // Pin weight regs so the allocator materializes them before the loop.
#pragma unroll
  for (int j = 0; j < 8; ++j)
#pragma unroll
    for (int p = 0; p < 24; ++p) asm volatile("" : "+v"(w2[j][p]));

  float c_reg = 0.f;
  if (kq < 2) c_reg = c0[dir * HH + u];
  if (t < 128)
    h2[0][t >> 5][t & 31] = pack_u(h0[dir * HH + t], h0[dir * HH + t + 128]);

  // prefetch Zx for step 0 (gate lanes)
  float zx0 = 0.f, zx1 = 0.f, zx2 = 0.f, zx3 = 0.f;
  if (kq < 2) {
    const int trow0 = dir ? (LL - 1) : 0;
    const float* zp = Z + (size_t)trow0 * NGATE + u;
    zx0 = zp[0]; zx1 = zp[HH]; zx2 = zp[2 * HH]; zx3 = zp[3 * HH];
  }
  __syncthreads();

  for (int s = 0; s < LL; ++s) {
    const int par = s & 1;
    // prefetch next step's Zx (hidden under the matvec)
    float nzx0 = 0.f, nzx1 = 0.f, nzx2 = 0.f, nzx3 = 0.f;
    if (kq < 2 && s + 1 < LL) {
      const int trow = dir ? (LL - 2 - s) : (s + 1);
      const float* zp = Z + (size_t)trow * NGATE + u;
      nzx0 = zp[0]; nzx1 = zp[HH]; nzx2 = zp[2 * HH]; nzx3 = zp[3 * HH];
    }

    // matvec: 8 rows x 32 pairs, f32 accumulate
    const unsigned* h2s = &h2[par][kq][0];
    float acc[8] = {0.f, 0.f, 0.f, 0.f, 0.f, 0.f, 0.f, 0.f};
#pragma unroll
    for (int c = 0; c < 8; ++c) {
      const uint4 hv = *reinterpret_cast<const uint4*>(h2s + (c << 2));
      const v2h hx = u2h(hv.x), hy = u2h(hv.y), hz = u2h(hv.z), hw = u2h(hv.w);
      if (c < 6) {
#pragma unroll
        for (int j = 0; j < 8; ++j) {
          acc[j] = __builtin_amdgcn_fdot2(w2[j][4 * c + 0], hx, acc[j], false);
          acc[j] = __builtin_amdgcn_fdot2(w2[j][4 * c + 1], hy, acc[j], false);
          acc[j] = __builtin_amdgcn_fdot2(w2[j][4 * c + 2], hz, acc[j], false);
          acc[j] = __builtin_amdgcn_fdot2(w2[j][4 * c + 3], hw, acc[j], false);
        }
      } else {
#pragma unroll
        for (int j = 0; j < 8; ++j) {
          const uint4 wv = wl[(((j << 1) | (c - 6)) << 9) + t];
          acc[j] = __builtin_amdgcn_fdot2(u2h(wv.x), hx, acc[j], false);
          acc[j] = __builtin_amdgcn_fdot2(u2h(wv.y), hy, acc[j], false);
          acc[j] = __builtin_amdgcn_fdot2(u2h(wv.z), hz, acc[j], false);
          acc[j] = __builtin_amdgcn_fdot2(u2h(wv.w), hw, acc[j], false);
        }
      }
    }

    // reduce k-partials across the quad (all lanes active)
#pragma unroll
    for (int j = 0; j < 8; ++j) {
      float v = acc[j];
      v += dpp_f<0xB1>(v);
      v += dpp_f<0x4E>(v);
      acc[j] = v;
    }

    if (kq < 2) {
      const bool hi = (kq == 1);
      const float z0 = zx0 + (hi ? acc[1] : acc[0]);
      const float z1 = zx1 + (hi ? acc[3] : acc[2]);
      const float z2 = zx2 + (hi ? acc[5] : acc[4]);
      const float z3 = zx3 + (hi ? acc[7] : acc[6]);
      const float ig = fsigmoid(z0);
      const float fg = fsigmoid(z1);
      const float gg = ftanh(z2);
      const float og = fsigmoid(z3);
      c_reg = fg * c_reg + ig * gg;
      const float hval = og * ftanh(c_reg);
      const int trow = dir ? (LL - 1 - s) : s;
      Hall[(size_t)trow * HH + u] = hval;
      // pack (h[rq], h[rq+128]) on the kq==0 lane via quad neighbor swap
      const float hnb = dpp_f<0xB1>(hval);
      if (kq == 0) {
        h2[(s + 1) & 1][rq >> 5][rq & 31] = pack_u(hval, hnb);
      }
    }
    __syncthreads();
    zx0 = nzx0; zx1 = nzx1; zx2 = nzx2; zx3 = nzx3;
  }
}

// ---------------------------------------------------------------------------
// Kernel 4: feats
// ---------------------------------------------------------------------------
__global__ __launch_bounds__(256) void feats_gemm(
    const float* __restrict__ HALL, const float* __restrict__ Wout,
    const float* __restrict__ bout, float* __restrict__ FE) {
  __shared__ float Wl[16][516];
  const int t = threadIdx.x;
  for (int i = t; i < 16 * 512; i += 256) Wl[i >> 9][i & 511] = Wout[i];
  __syncthreads();
  const int row = blockIdx.x * 16 + (t >> 4);
  const int j = t & 15;
  const float* hf = HALL + (size_t)row * HH;
  const float* hb = HALL + (size_t)LL * HH + (size_t)row * HH;
  float acc = bout[j];
  for (int k = 0; k < HH; k += 4) {
    const float4 a = *reinterpret_cast<const float4*>(hf + k);
    const float4 wa = *reinterpret_cast<const float4*>(&Wl[j][k]);
    acc += a.x * wa.x + a.y * wa.y + a.z * wa.z + a.w * wa.w;
    const float4 b2 = *reinterpret_cast<const float4*>(hb + k);
    const float4 wb = *reinterpret_cast<const float4*>(&Wl[j][256 + k]);
    acc += b2.x * wb.x + b2.y * wb.y + b2.z * wb.z + b2.w * wb.w;
  }
  FE[(size_t)row * TT + j] = acc;
}

// ---------------------------------------------------------------------------
// Kernel 5: Viterbi (unchanged)
// ---------------------------------------------------------------------------
__global__ __launch_bounds__(1024) void viterbi(
    const float* __restrict__ FE, const float* __restrict__ trans,
    float* __restrict__ out) {
  __shared__ unsigned char bp8[LL * TT];
  __shared__ unsigned char xc[64 * 16];
  __shared__ unsigned char entry[64];
  __shared__ int sbest;
  const int t = threadIdx.x;

  if (t < 64) {
    const int n = t >> 2, pg = t & 3;
    const float tr0 = trans[n * 16 + (pg << 2) + 0];
    const float tr1 = trans[n * 16 + (pg << 2) + 1];
    const float tr2 = trans[n * 16 + (pg << 2) + 2];
    const float tr3 = trans[n * 16 + (pg << 2) + 3];
    float fvp0 = ((pg << 2) + 0 == 14) ? 0.f : NEGV;
    float fvp1 = ((pg << 2) + 1 == 14) ? 0.f : NEGV;
    float fvp2 = ((pg << 2) + 2 == 14) ? 0.f : NEGV;
    float fvp3 = ((pg << 2) + 3 == 14) ? 0.f : NEGV;

    auto step = [&](int s, float feat) {
      float bv = fvp0 + tr0; int bi = (pg << 2);
      float c;
      c = fvp1 + tr1; if (c > bv) { bv = c; bi = (pg << 2) + 1; }
      c = fvp2 + tr2; if (c > bv) { bv = c; bi = (pg << 2) + 2; }
      c = fvp3 + tr3; if (c > bv) { bv = c; bi = (pg << 2) + 3; }
      float pv = dpp_f<0xB1>(bv); int pi = dpp_i<0xB1>(bi);
      if (pv > bv || (pv == bv && pi < bi)) { bv = pv; bi = pi; }
      pv = dpp_f<0x4E>(bv); pi = dpp_i<0x4E>(bi);
      if (pv > bv || (pv == bv && pi < bi)) { bv = pv; bi = pi; }
      if (pg == 0) bp8[(s << 4) + n] = (unsigned char)bi;
      const float fvn = bv + feat;
      fvp0 = bperm_f((pg << 4) + 0,  fvn);
      fvp1 = bperm_f((pg << 4) + 4,  fvn);
      fvp2 = bperm_f((pg << 4) + 8,  fvn);
      fvp3 = bperm_f((pg << 4) + 12, fvn);
    };

    float fb0 = FE[(0 << 4) + n], fb1 = FE[(1 << 4) + n];
    float fb2 = FE[(2 << 4) + n], fb3 = FE[(3 << 4) + n];
    for (int s = 0; s < LL; s += 4) {
      step(s + 0, fb0); fb0 = (s + 4 < LL) ? FE[((s + 4) << 4) + n] : 0.f;
      step(s + 1, fb1); fb1 = (s + 5 < LL) ? FE[((s + 5) << 4) + n] : 0.f;
      step(s + 2, fb2); fb2 = (s + 6 < LL) ? FE[((s + 6) << 4) + n] : 0.f;
      step(s + 3, fb3); fb3 = (s + 7 < LL) ? FE[((s + 7) << 4) + n] : 0.f;
    }

    const float tt0 = trans[240 + (pg << 2) + 0];
    const float tt1 = trans[240 + (pg << 2) + 1];
    const float tt2 = trans[240 + (pg << 2) + 2];
    const float tt3 = trans[240 + (pg << 2) + 3];
    float bv = fvp0 + tt0; int bi = (pg << 2);
    float c;
    c = fvp1 + tt1; if (c > bv) { bv = c; bi = (pg << 2) + 1; }
    c = fvp2 + tt2; if (c > bv) { bv = c; bi = (pg << 2) + 2; }
    c = fvp3 + tt3; if (c > bv) { bv = c; bi = (pg << 2) + 3; }
    float pv = dpp_f<0xB1>(bv); int pi = dpp_i<0xB1>(bi);
    if (pv > bv || (pv == bv && pi < bi)) { bv = pv; bi = pi; }
    pv = dpp_f<0x4E>(bv); pi = dpp_i<0x4E>(bi);
    if (pv > bv || (pv == bv && pi < bi)) { bv = pv; bi = pi; }
    if (t == 0) { out[0] = bv; sbest = bi; }
  }
  __syncthreads();

  {
    const int c = t >> 4, e = t & 15;
    int tag = e;
#pragma unroll 1
    for (int i = 63; i >= 0; --i) tag = bp8[(((c << 6) + i) << 4) + tag];
    xc[(c << 4) + e] = (unsigned char)tag;
  }
  __syncthreads();
  if (t == 0) {
    int carry = sbest;
#pragma unroll 1
    for (int c = 63; c >= 0; --c) {
      entry[c] = (unsigned char)carry;
      carry = xc[(c << 4) + carry];
    }
  }
  __syncthreads();
  if (t < 64) {
    const int c = t;
    int tag = entry[c];
#pragma unroll 1
    for (int i = 63; i >= 0; --i) {
      const int s = (c << 6) + i;
      out[1 + s] = (float)tag;
      tag = bp8[(s << 4) + tag];
    }
  }
}

// ---------------------------------------------------------------------------
extern "C" void kernel_launch(void* const* d_in, const int* in_sizes, int n_in,
                              void* d_out, int out_size, void* d_ws, size_t ws_size,
                              hipStream_t stream) {
  const int*   sent = (const int*)d_in[0];
  const float* emb  = (const float*)d_in[1];
  const float* wihf = (const float*)d_in[2];
  const float* whhf = (const float*)d_in[3];
  const float* bf   = (const float*)d_in[4];
  const float* wihb = (const float*)d_in[5];
  const float* whhb = (const float*)d_in[6];
  const float* bb   = (const float*)d_in[7];
  const float* wout = (const float*)d_in[8];
  const float* bout = (const float*)d_in[9];
  const float* trans= (const float*)d_in[10];
  const float* h0   = (const float*)d_in[11];
  const float* c0   = (const float*)d_in[12];
  float* out = (float*)d_out;
  char* ws = (char*)d_ws;

  float* X    = (float*)(ws + OFF_X);
  float* ZX   = (float*)(ws + OFF_ZX);
  float* HALL = (float*)(ws + OFF_HALL);
  float* FE   = (float*)(ws + OFF_FE);

  gather_x<<<(LL * (EE / 4) + 255) / 256, 256, 0, stream>>>(sent, emb, X);
  input_gemm<<<dim3(16, 64, 2), 256, 0, stream>>>(X, wihf, bf, wihb, bb, ZX);
  recurrence<<<2, 512, 0, stream>>>(whhf, whhb, h0, c0, ZX, HALL);
  feats_gemm<<<LL / 16, 256, 0, stream>>>(HALL, wout, bout, FE);
  viterbi<<<1, 1024, 0, stream>>>(FE, trans, out);
}

// Round 2
// 7237.817 us; speedup vs baseline: 1.0909x; 1.0909x over previous
//
#include <hip/hip_runtime.h>
#include <math.h>
#include <stdint.h>

// Problem constants
constexpr int LL = 4096;   // seq len
constexpr int EE = 300;    // embedding dim
constexpr int HH = 256;    // per-direction hidden (H2)
constexpr int NGATE = 1024;// 4*HH
constexpr int TT = 16;     // tagset
constexpr float NEGV = -10000.0f;

typedef _Float16 v2h __attribute__((ext_vector_type(2)));
typedef _Float16 v8h __attribute__((ext_vector_type(8)));
typedef float v4f __attribute__((ext_vector_type(4)));

// Workspace layout (byte offsets)
constexpr size_t OFF_X    = 16384;
constexpr size_t OFF_ZX   = OFF_X    + (size_t)LL*EE*4;     // 2*L*1024 f32
constexpr size_t OFF_HALL = OFF_ZX   + (size_t)2*LL*NGATE*4;// 2*L*256 f32
constexpr size_t OFF_FE   = OFF_HALL + (size_t)2*LL*HH*4;   // L*16 f32

__device__ __forceinline__ v2h pack_h2(float x, float y) {
  return __builtin_bit_cast(v2h, __builtin_amdgcn_cvt_pkrtz(x, y));
}
__device__ __forceinline__ unsigned pack_u(float x, float y) {
  return __builtin_bit_cast(unsigned, __builtin_amdgcn_cvt_pkrtz(x, y));
}
__device__ __forceinline__ v8h make_v8h(v2h a, v2h b, v2h c, v2h d) {
  union { v2h p[4]; v8h v; } u; u.p[0]=a; u.p[1]=b; u.p[2]=c; u.p[3]=d; return u.v;
}

__device__ __forceinline__ float fsigmoid(float x) {
  return __builtin_amdgcn_rcpf(1.f + __expf(-x));
}
__device__ __forceinline__ float ftanh(float x) {
  return 1.f - 2.f * __builtin_amdgcn_rcpf(1.f + __expf(2.f * x));
}

template <int CTRL>
__device__ __forceinline__ int dpp_i(int v) {
  return __builtin_amdgcn_mov_dpp(v, CTRL, 0xF, 0xF, true);
}
template <int CTRL>
__device__ __forceinline__ float dpp_f(float v) {
  return __int_as_float(__builtin_amdgcn_mov_dpp(__float_as_int(v), CTRL, 0xF, 0xF, true));
}
__device__ __forceinline__ float bperm_f(int lane, float v) {
  return __int_as_float(__builtin_amdgcn_ds_bpermute(lane << 2, __float_as_int(v)));
}

// ---------------------------------------------------------------------------
// Kernel 1: embedding gather
// ---------------------------------------------------------------------------
__global__ void gather_x(const int* __restrict__ sent, const float* __restrict__ emb,
                         float* __restrict__ X) {
  const int i = blockIdx.x * blockDim.x + threadIdx.x;
  const int total = LL * (EE / 4);
  if (i >= total) return;
  const int row = i / (EE / 4), c4 = i % (EE / 4);
  const int v = sent[row];
  reinterpret_cast<float4*>(X)[(size_t)row * (EE / 4) + c4] =
      reinterpret_cast<const float4*>(emb + (size_t)v * EE)[c4];
}

// ---------------------------------------------------------------------------
// Kernel 2: input GEMM  Zx[dir][t][n] = X[t]·W_ih[n] + b[n]
// ---------------------------------------------------------------------------
__global__ __launch_bounds__(256) void input_gemm(
    const float* __restrict__ X, const float* __restrict__ w_f,
    const float* __restrict__ b_f, const float* __restrict__ w_b,
    const float* __restrict__ b_b, float* __restrict__ ZX) {
  const int dir = blockIdx.z;
  const float* __restrict__ W  = dir ? w_b : w_f;
  const float* __restrict__ Bv = dir ? b_b : b_f;
  float* __restrict__ Z = ZX + (size_t)dir * LL * NGATE;
  __shared__ float As[32][68];
  __shared__ float Bs[32][68];
  const int m0 = blockIdx.y * 64, n0 = blockIdx.x * 64;
  const int t = threadIdx.x;
  const int tx = t & 15, ty = t >> 4;
  float acc[4][4] = {};
  for (int k0 = 0; k0 < EE; k0 += 32) {
#pragma unroll
    for (int r = 0; r < 2; ++r) {
      const int idx = t + r * 256;
      const int row = idx >> 3;
      const int kk4 = (idx & 7) << 2;
      const int k = k0 + kk4;
      float4 va = make_float4(0.f, 0.f, 0.f, 0.f), vb = va;
      if (k < EE) {
        va = *reinterpret_cast<const float4*>(X + (size_t)(m0 + row) * EE + k);
        vb = *reinterpret_cast<const float4*>(W + (size_t)(n0 + row) * EE + k);
      }
      As[kk4 + 0][row] = va.x; As[kk4 + 1][row] = va.y;
      As[kk4 + 2][row] = va.z; As[kk4 + 3][row] = va.w;
      Bs[kk4 + 0][row] = vb.x; Bs[kk4 + 1][row] = vb.y;
      Bs[kk4 + 2][row] = vb.z; Bs[kk4 + 3][row] = vb.w;
    }
    __syncthreads();
    const int kmax = (EE - k0 < 32) ? (EE - k0) : 32;
    for (int k = 0; k < kmax; ++k) {
      const float4 av = *reinterpret_cast<const float4*>(&As[k][ty << 2]);
      const float4 bv = *reinterpret_cast<const float4*>(&Bs[k][tx << 2]);
      acc[0][0] += av.x * bv.x; acc[0][1] += av.x * bv.y; acc[0][2] += av.x * bv.z; acc[0][3] += av.x * bv.w;
      acc[1][0] += av.y * bv.x; acc[1][1] += av.y * bv.y; acc[1][2] += av.y * bv.z; acc[1][3] += av.y * bv.w;
      acc[2][0] += av.z * bv.x; acc[2][1] += av.z * bv.y; acc[2][2] += av.z * bv.z; acc[2][3] += av.z * bv.w;
      acc[3][0] += av.w * bv.x; acc[3][1] += av.w * bv.y; acc[3][2] += av.w * bv.z; acc[3][3] += av.w * bv.w;
    }
    __syncthreads();
  }
#pragma unroll
  for (int i = 0; i < 4; ++i)
#pragma unroll
    for (int j = 0; j < 4; ++j) {
      const int m = m0 + (ty << 2) + i, n = n0 + (tx << 2) + j;
      Z[(size_t)m * NGATE + n] = acc[i][j] + Bv[n];
    }
}

// ---------------------------------------------------------------------------
// Kernel 3: persistent bidirectional LSTM recurrence — one WG per direction,
// matvec via v_mfma_f32_16x16x32_f16.
//
// R1 post-mortem: fdot2 with 192 f16-pair weight VGPRs => allocator stashed
// weights in AGPRs (VGPR_Count 128) and inserted per-use accvgpr_read moves
// (~1500 extra cy/step; per-CU VALUBusy ~70%). fdot2 cannot read AGPRs.
// MFMA CAN read AGPR operands natively => AGPR-resident weights are free.
//
// Layout (wave w owns n in [w*128, (w+1)*128), 8 tiles of 16):
//   B-frag (tile tn, chunk kc): lane l supplies W[w*128+tn*16+(l&15)]
//     [kc*32 + (l>>4)*8 + j], j=0..7  (f16, 4 VGPRs per frag)
//   A-frag: h replicated across all 16 rows: lane l reads h[kc*32+(l>>4)*8..+8]
//     (row-mapping immune; A/B share the (quadrant,slot)->k map so any HW
//      k-permutation cancels; C/D read uses only col=lane&15 — m89-verified)
//   45 frags/wave in regs (180 v), 19 frags/wave in LDS (152 KB, b128 reads)
// Per step: MFMA phase -> z to zbuf -> barrier -> gate math on t<256 ->
// h16 (f16, parity dbuf) -> barrier.  ~614 cy MFMA-pipe/SIMD/step.
// ---------------------------------------------------------------------------
__global__ __launch_bounds__(512) __attribute__((amdgpu_waves_per_eu(2, 2)))
void recurrence(
    const float* __restrict__ whh_f, const float* __restrict__ whh_b,
    const float* __restrict__ h0, const float* __restrict__ c0,
    const float* __restrict__ ZX, float* __restrict__ HALL) {
  const int dir = blockIdx.x;
  const int t = threadIdx.x;
  const int w = t >> 6;            // wave 0..7
  const int l = t & 63;
  const int lcol = l & 15;
  const int lq = l >> 4;           // quadrant 0..3
  const float* __restrict__ Whh = dir ? whh_b : whh_f;
  const float* __restrict__ Z = ZX + (size_t)dir * LL * NGATE;
  float* __restrict__ Hall = HALL + (size_t)dir * LL * HH;

  __shared__ uint4 WL[8 * 19 * 64];          // 152 KB: LDS-resident B-frags
  __shared__ float zbuf[NGATE];              // 4 KB: z exchange
  __shared__ unsigned h16u[2 * 128];         // 1 KB: packed f16 h, parity dbuf

  // ---- preamble: build B-frags from W_hh (f32 -> f16 RTZ) ---------------
  v8h breg[45];
#pragma unroll
  for (int kc = 0; kc < 8; ++kc) {
#pragma unroll
    for (int tn = 0; tn < 8; ++tn) {
      const int g = kc * 8 + tn;
      const int n = (w << 7) + (tn << 4) + lcol;
      const int kb = (kc << 5) + (lq << 3);
      const float* wp = Whh + (size_t)n * HH + kb;
      const float4 a4 = *reinterpret_cast<const float4*>(wp);
      const float4 b4 = *reinterpret_cast<const float4*>(wp + 4);
      const v8h f = make_v8h(pack_h2(a4.x, a4.y), pack_h2(a4.z, a4.w),
                             pack_h2(b4.x, b4.y), pack_h2(b4.z, b4.w));
      if (g < 45) {
        breg[g] = f;
      } else {
        WL[(w * 19 + (g - 45)) * 64 + l] = __builtin_bit_cast(uint4, f);
      }
    }
  }

  // ---- state init --------------------------------------------------------
  float c_reg = 0.f;
  if (t < 256) c_reg = c0[dir * HH + t];
  if (t < 128)
    h16u[t] = pack_u(h0[dir * HH + 2 * t], h0[dir * HH + 2 * t + 1]);

  // prefetch Zx for step 0 (gate threads)
  float zx0 = 0.f, zx1 = 0.f, zx2 = 0.f, zx3 = 0.f;
  if (t < 256) {
    const int trow0 = dir ? (LL - 1) : 0;
    const float* zp = Z + (size_t)trow0 * NGATE + t;
    zx0 = zp[0]; zx1 = zp[HH]; zx2 = zp[2 * HH]; zx3 = zp[3 * HH];
  }
  __syncthreads();

  const char* h16b = reinterpret_cast<const char*>(h16u);

  for (int s = 0; s < LL; ++s) {
    const int par = s & 1;
    // prefetch next step's Zx (hidden under the MFMA phase)
    float nzx0 = 0.f, nzx1 = 0.f, nzx2 = 0.f, nzx3 = 0.f;
    if (t < 256 && s + 1 < LL) {
      const int trow = dir ? (LL - 2 - s) : (s + 1);
      const float* zp = Z + (size_t)trow * NGATE + t;
      nzx0 = zp[0]; nzx1 = zp[HH]; nzx2 = zp[2 * HH]; nzx3 = zp[3 * HH];
    }

    // ---- MFMA phase: z[n] = sum_k W[n][k] h[k] ---------------------------
    v4f acc0 = {0.f,0.f,0.f,0.f}, acc1 = {0.f,0.f,0.f,0.f};
    v4f acc2 = {0.f,0.f,0.f,0.f}, acc3 = {0.f,0.f,0.f,0.f};
    v4f acc4 = {0.f,0.f,0.f,0.f}, acc5 = {0.f,0.f,0.f,0.f};
    v4f acc6 = {0.f,0.f,0.f,0.f}, acc7 = {0.f,0.f,0.f,0.f};
#pragma unroll
    for (int kc = 0; kc < 8; ++kc) {
      const uint4 hv = *reinterpret_cast<const uint4*>(
          h16b + (par << 9) + (kc << 6) + (lq << 4));
      const v8h ah = __builtin_bit_cast(v8h, hv);
#pragma unroll
      for (int tn = 0; tn < 8; ++tn) {
        const int g = kc * 8 + tn;
        v8h bw;
        if (g < 45) bw = breg[g];
        else bw = __builtin_bit_cast(v8h, WL[(w * 19 + (g - 45)) * 64 + l]);
        v4f* accp = (tn==0)?&acc0:(tn==1)?&acc1:(tn==2)?&acc2:(tn==3)?&acc3:
                    (tn==4)?&acc4:(tn==5)?&acc5:(tn==6)?&acc6:&acc7;
        *accp = __builtin_amdgcn_mfma_f32_16x16x32_f16(ah, bw, *accp, 0, 0, 0);
      }
    }
    // z-write: with replicated A rows, every lane's acc[tn][0] == z[n(tn,lcol)]
    const float zlo = (lq==0)?acc0[0]:(lq==1)?acc1[0]:(lq==2)?acc2[0]:acc3[0];
    const float zhi = (lq==0)?acc4[0]:(lq==1)?acc5[0]:(lq==2)?acc6[0]:acc7[0];
    zbuf[(w << 7) + (lq << 4) + lcol] = zlo;
    zbuf[(w << 7) + 64 + (lq << 4) + lcol] = zhi;
    __syncthreads();

    // ---- gate phase (unit u = t, threads 0..255) -------------------------
    if (t < 256) {
      const float z0 = zx0 + zbuf[t];
      const float z1 = zx1 + zbuf[256 + t];
      const float z2 = zx2 + zbuf[512 + t];
      const float z3 = zx3 + zbuf[768 + t];
      const float ig = fsigmoid(z0);
      const float fg = fsigmoid(z1);
      const float gg = ftanh(z2);
      const float og = fsigmoid(z3);
      c_reg = fg * c_reg + ig * gg;
      const float hval = og * ftanh(c_reg);
      const int trow = dir ? (LL - 1 - s) : s;
      Hall[(size_t)trow * HH + t] = hval;
      const float hnb = dpp_f<0xB1>(hval);   // neighbor (t^1) within wave
      if ((t & 1) == 0)
        h16u[((par ^ 1) << 7) + (t >> 1)] = pack_u(hval, hnb);
    }
    __syncthreads();
    zx0 = nzx0; zx1 = nzx1; zx2 = nzx2; zx3 = nzx3;
  }
}

// ---------------------------------------------------------------------------
// Kernel 4: feats
// ---------------------------------------------------------------------------
__global__ __launch_bounds__(256) void feats_gemm(
    const float* __restrict__ HALL, const float* __restrict__ Wout,
    const float* __restrict__ bout, float* __restrict__ FE) {
  __shared__ float Wl[16][516];
  const int t = threadIdx.x;
  for (int i = t; i < 16 * 512; i += 256) Wl[i >> 9][i & 511] = Wout[i];
  __syncthreads();
  const int row = blockIdx.x * 16 + (t >> 4);
  const int j = t & 15;
  const float* hf = HALL + (size_t)row * HH;
  const float* hb = HALL + (size_t)LL * HH + (size_t)row * HH;
  float acc = bout[j];
  for (int k = 0; k < HH; k += 4) {
    const float4 a = *reinterpret_cast<const float4*>(hf + k);
    const float4 wa = *reinterpret_cast<const float4*>(&Wl[j][k]);
    acc += a.x * wa.x + a.y * wa.y + a.z * wa.z + a.w * wa.w;
    const float4 b2 = *reinterpret_cast<const float4*>(hb + k);
    const float4 wb = *reinterpret_cast<const float4*>(&Wl[j][256 + k]);
    acc += b2.x * wb.x + b2.y * wb.y + b2.z * wb.z + b2.w * wb.w;
  }
  FE[(size_t)row * TT + j] = acc;
}

// ---------------------------------------------------------------------------
// Kernel 5: Viterbi (unchanged)
// ---------------------------------------------------------------------------
__global__ __launch_bounds__(1024) void viterbi(
    const float* __restrict__ FE, const float* __restrict__ trans,
    float* __restrict__ out) {
  __shared__ unsigned char bp8[LL * TT];
  __shared__ unsigned char xc[64 * 16];
  __shared__ unsigned char entry[64];
  __shared__ int sbest;
  const int t = threadIdx.x;

  if (t < 64) {
    const int n = t >> 2, pg = t & 3;
    const float tr0 = trans[n * 16 + (pg << 2) + 0];
    const float tr1 = trans[n * 16 + (pg << 2) + 1];
    const float tr2 = trans[n * 16 + (pg << 2) + 2];
    const float tr3 = trans[n * 16 + (pg << 2) + 3];
    float fvp0 = ((pg << 2) + 0 == 14) ? 0.f : NEGV;
    float fvp1 = ((pg << 2) + 1 == 14) ? 0.f : NEGV;
    float fvp2 = ((pg << 2) + 2 == 14) ? 0.f : NEGV;
    float fvp3 = ((pg << 2) + 3 == 14) ? 0.f : NEGV;

    auto step = [&](int s, float feat) {
      float bv = fvp0 + tr0; int bi = (pg << 2);
      float c;
      c = fvp1 + tr1; if (c > bv) { bv = c; bi = (pg << 2) + 1; }
      c = fvp2 + tr2; if (c > bv) { bv = c; bi = (pg << 2) + 2; }
      c = fvp3 + tr3; if (c > bv) { bv = c; bi = (pg << 2) + 3; }
      float pv = dpp_f<0xB1>(bv); int pi = dpp_i<0xB1>(bi);
      if (pv > bv || (pv == bv && pi < bi)) { bv = pv; bi = pi; }
      pv = dpp_f<0x4E>(bv); pi = dpp_i<0x4E>(bi);
      if (pv > bv || (pv == bv && pi < bi)) { bv = pv; bi = pi; }
      if (pg == 0) bp8[(s << 4) + n] = (unsigned char)bi;
      const float fvn = bv + feat;
      fvp0 = bperm_f((pg << 4) + 0,  fvn);
      fvp1 = bperm_f((pg << 4) + 4,  fvn);
      fvp2 = bperm_f((pg << 4) + 8,  fvn);
      fvp3 = bperm_f((pg << 4) + 12, fvn);
    };

    float fb0 = FE[(0 << 4) + n], fb1 = FE[(1 << 4) + n];
    float fb2 = FE[(2 << 4) + n], fb3 = FE[(3 << 4) + n];
    for (int s = 0; s < LL; s += 4) {
      step(s + 0, fb0); fb0 = (s + 4 < LL) ? FE[((s + 4) << 4) + n] : 0.f;
      step(s + 1, fb1); fb1 = (s + 5 < LL) ? FE[((s + 5) << 4) + n] : 0.f;
      step(s + 2, fb2); fb2 = (s + 6 < LL) ? FE[((s + 6) << 4) + n] : 0.f;
      step(s + 3, fb3); fb3 = (s + 7 < LL) ? FE[((s + 7) << 4) + n] : 0.f;
    }

    const float tt0 = trans[240 + (pg << 2) + 0];
    const float tt1 = trans[240 + (pg << 2) + 1];
    const float tt2 = trans[240 + (pg << 2) + 2];
    const float tt3 = trans[240 + (pg << 2) + 3];
    float bv = fvp0 + tt0; int bi = (pg << 2);
    float c;
    c = fvp1 + tt1; if (c > bv) { bv = c; bi = (pg << 2) + 1; }
    c = fvp2 + tt2; if (c > bv) { bv = c; bi = (pg << 2) + 2; }
    c = fvp3 + tt3; if (c > bv) { bv = c; bi = (pg << 2) + 3; }
    float pv = dpp_f<0xB1>(bv); int pi = dpp_i<0xB1>(bi);
    if (pv > bv || (pv == bv && pi < bi)) { bv = pv; bi = pi; }
    pv = dpp_f<0x4E>(bv); pi = dpp_i<0x4E>(bi);
    if (pv > bv || (pv == bv && pi < bi)) { bv = pv; bi = pi; }
    if (t == 0) { out[0] = bv; sbest = bi; }
  }
  __syncthreads();

  {
    const int c = t >> 4, e = t & 15;
    int tag = e;
#pragma unroll 1
    for (int i = 63; i >= 0; --i) tag = bp8[(((c << 6) + i) << 4) + tag];
    xc[(c << 4) + e] = (unsigned char)tag;
  }
  __syncthreads();
  if (t == 0) {
    int carry = sbest;
#pragma unroll 1
    for (int c = 63; c >= 0; --c) {
      entry[c] = (unsigned char)carry;
      carry = xc[(c << 4) + carry];
    }
  }
  __syncthreads();
  if (t < 64) {
    const int c = t;
    int tag = entry[c];
#pragma unroll 1
    for (int i = 63; i >= 0; --i) {
      const int s = (c << 6) + i;
      out[1 + s] = (float)tag;
      tag = bp8[(s << 4) + tag];
    }
  }
}

// ---------------------------------------------------------------------------
extern "C" void kernel_launch(void* const* d_in, const int* in_sizes, int n_in,
                              void* d_out, int out_size, void* d_ws, size_t ws_size,
                              hipStream_t stream) {
  const int*   sent = (const int*)d_in[0];
  const float* emb  = (const float*)d_in[1];
  const float* wihf = (const float*)d_in[2];
  const float* whhf = (const float*)d_in[3];
  const float* bf   = (const float*)d_in[4];
  const float* wihb = (const float*)d_in[5];
  const float* whhb = (const float*)d_in[6];
  const float* bb   = (const float*)d_in[7];
  const float* wout = (const float*)d_in[8];
  const float* bout = (const float*)d_in[9];
  const float* trans= (const float*)d_in[10];
  const float* h0   = (const float*)d_in[11];
  const float* c0   = (const float*)d_in[12];
  float* out = (float*)d_out;
  char* ws = (char*)d_ws;

  float* X    = (float*)(ws + OFF_X);
  float* ZX   = (float*)(ws + OFF_ZX);
  float* HALL = (float*)(ws + OFF_HALL);
  float* FE   = (float*)(ws + OFF_FE);

  gather_x<<<(LL * (EE / 4) + 255) / 256, 256, 0, stream>>>(sent, emb, X);
  input_gemm<<<dim3(16, 64, 2), 256, 0, stream>>>(X, wihf, bf, wihb, bb, ZX);
  recurrence<<<2, 512, 0, stream>>>(whhf, whhb, h0, c0, ZX, HALL);
  feats_gemm<<<LL / 16, 256, 0, stream>>>(HALL, wout, bout, FE);
  viterbi<<<1, 1024, 0, stream>>>(FE, trans, out);
}